// Round 8
// baseline (589.842 us; speedup 1.0000x reference)
//
#include <hip/hip_runtime.h>

// Fused 2-layer LSTM (B=4096, S=512, H=64) + dense(64->32 relu)->dense(32->24).
// R11: R3 shape (grid=256 -> 1 WG/CU, 512 thr, 8 waves = (layer, col-tile),
// 16 rows/WG) with the per-step __syncthreads REPLACED by flag-based
// producer/consumer sync. R4-R10 showed the WG-wide barrier is the bottleneck:
// all waves stall at one program point; 2-WG/CU attempts all died to the
// compiler's register-allocation constraint box (64-VGPR clamp or AGPR slush
// pushing per-wave totals past 128 -> second WG evicted, R10 occ 23.5%).
// Here the dependency is made explicit and one-directional:
//   prog1[4], prog2[4]: per-wave monotonic step counters in LDS.
//   h1 = depth-4 ring. L1 wave @t waits min(prog1)>=t (peers' h1[t-1])
//        && min(prog2)>=t-2 (ring slot t&3 free). L1 runs up to 2 ahead.
//   h2 = 2-slot parity. L2 wave @t waits min(prog1)>=t && min(prog2)>=t.
//   Publish: ds_writes -> __threadfence_block -> lane0 writes prog[w]=t+1.
//   Consume: volatile broadcast reads + compiler memory barrier after spin.
// Each SIMD hosts one L1 + one L2 wave: their serial chains (ds_read latency,
// MFMA chains, exp chains) now interleave instead of stalling in lockstep.
// 1 WG/CU = full 256-VGPR headroom at 2 waves/SIMD: spill-proof by design.
// Recurrence: layer-2 delayed 1 step (z2[t-1] = b2 + Wih2@h1[t-1] + Whh2@h2[t-2]).
// Gate math: 5 exp + 2 rcp per element (i/f/g denominators merged).

typedef __attribute__((ext_vector_type(8))) short bf16x8;
typedef __attribute__((ext_vector_type(4))) float floatx4;

#define SEQ 512
#define HID 64
#define LOG2E 1.4426950408889634f

__device__ inline floatx4 MFMA(bf16x8 a, bf16x8 b, floatx4 c) {
    return __builtin_amdgcn_mfma_f32_16x16x32_bf16(a, b, c, 0, 0, 0);
}
__device__ inline short f2bf(float f) {
    __bf16 b = (__bf16)f;
    return __builtin_bit_cast(short, b);
}
__device__ inline float exp2_fast(float x) {
#if __has_builtin(__builtin_amdgcn_exp2f)
    return __builtin_amdgcn_exp2f(x);
#else
    return __expf(x * 0.6931471805599453f);
#endif
}
__device__ inline float rcp_fast(float x) { return __builtin_amdgcn_rcpf(x); }

__device__ inline int min4v(volatile int* p) {
    return min(min(p[0], p[1]), min(p[2], p[3]));
}

// z* pre-scaled: zi=-i*log2e, zf=-f*log2e, zg=-2g*log2e, zo=-o*log2e.
// c' = [c*(1+ei)(1+eg) + (1-eg)(1+ef)] / [(1+ef)(1+ei)(1+eg)]  (merged rcp)
// h  = sigm(o)*tanh(c') = (1-ec)/((1+eo)(1+ec)),  ec = e^{-2c'} (clamped)
__device__ inline float lstm_gate(float zi, float zf, float zg, float zo, float& c) {
    float ei = exp2_fast(zi);
    float ef = exp2_fast(zf);
    float eg = exp2_fast(zg);
    float eo = exp2_fast(zo);
    float P  = (1.0f + ei) * (1.0f + eg);
    float F  = 1.0f + ef;
    float num = c * P + (1.0f - eg) * F;
    c = num * rcp_fast(P * F);
    float ec = exp2_fast(fminf(c * (-2.0f * LOG2E), 40.0f));
    return (1.0f - ec) * rcp_fast((1.0f + eo) * (1.0f + ec));
}

__global__ __launch_bounds__(512, 2)
void lstm_fused(
    const float* __restrict__ x,
    const float* __restrict__ Wih1, const float* __restrict__ Whh1,
    const float* __restrict__ bih1, const float* __restrict__ bhh1,
    const float* __restrict__ Wih2, const float* __restrict__ Whh2,
    const float* __restrict__ bih2, const float* __restrict__ bhh2,
    const float* __restrict__ Wd1,  const float* __restrict__ bd1,
    const float* __restrict__ Wd2,  const float* __restrict__ bd2,
    float* __restrict__ out)
{
    const int tid  = threadIdx.x;
    const int wid  = tid >> 6;        // 0..7
    const int ct   = wid & 3;         // column-tile (h-cols [16ct,16ct+16))
    const int is2  = wid >> 2;        // waves 0-3: layer-1, 4-7: layer-2
    const int lane = tid & 63;
    const int l15  = lane & 15;
    const int quad = lane >> 4;
    const int b0   = blockIdx.x * 16;

    __shared__ __align__(16) float x_s[16][516];
    __shared__ __align__(16) short h1_s[4][16][72];   // depth-4 ring
    __shared__ __align__(16) short h2_s[2][16][72];   // parity
    __shared__ float y1_s[16][32];
    __shared__ __align__(16) int prog1[4];
    __shared__ __align__(16) int prog2[4];
    // Pad LDS past 80KB: hard 1 WG/CU -> even dispatch + full VGPR headroom.
    __shared__ float pad_s[8448];
    if (blockIdx.x == 0xFFFFFFFFu) ((volatile float*)pad_s)[tid] = 1.0f;  // never true; keeps pad_s allocated

    // ---- stage x tile (16 rows x 512 f32) ----
    {
        const int row = tid >> 5;
        const int c0  = (tid & 31) * 16;
        const float4* src = reinterpret_cast<const float4*>(x + (size_t)(b0 + row) * SEQ + c0);
        float4* dst = reinterpret_cast<float4*>(&x_s[row][c0]);
        #pragma unroll
        for (int j = 0; j < 4; ++j) dst[j] = src[j];
    }
    for (int i = tid; i < 4 * 16 * 72; i += 512) (&h1_s[0][0][0])[i] = 0;
    for (int i = tid; i < 2 * 16 * 72; i += 512) (&h2_s[0][0][0])[i] = 0;
    if (tid < 4) { prog1[tid] = 0; prog2[tid] = 0; }

    const int hcol = ct * 16 + l15;
    volatile int* vp1 = prog1;
    volatile int* vp2 = prog2;

    __syncthreads();   // covers x stage, h zero, prog init

    if (!is2) {
        // ================= layer-1 waves (producer) =================
        bf16x8 Wf[2][4];                 // Whh1 K-halves
        float wxc[4], bcs[4];
        #pragma unroll
        for (int g = 0; g < 4; ++g) {
            const float sc = (g == 2) ? (-2.0f * LOG2E) : (-LOG2E);
            const int col = g * 64 + hcol;
            wxc[g] = Wih1[col] * sc;
            bcs[g] = (bih1[col] + bhh1[col]) * sc;
            #pragma unroll
            for (int kt = 0; kt < 2; ++kt) {
                const int koff = kt * 32 + quad * 8;
                union { short s[8]; bf16x8 v; } u;
                #pragma unroll
                for (int j = 0; j < 8; ++j)
                    u.s[j] = f2bf(Whh1[col * HID + koff + j] * sc);
                Wf[kt][g] = u.v;
            }
        }
        float cst[4] = {0, 0, 0, 0};
        int m1 = 0, m2 = 0;
        for (int t = 0; t < SEQ; ++t) {
            const int rs = (t - 1) & 3;    // h1[t-1] ring slot
            const int ws = t & 3;          // h1[t] ring slot
            // wait: peers' h1[t-1] ready; L2 consumed h1[t-4] (ring safety)
            if (m1 < t || m2 < t - 2) {
                do {
                    m1 = min4v(vp1);
                    m2 = min4v(vp2);
                } while (m1 < t || m2 < t - 2);
            }
            asm volatile("" ::: "memory");
            const bf16x8 A1a = *reinterpret_cast<const bf16x8*>(&h1_s[rs][l15][quad * 8]);
            const bf16x8 A1b = *reinterpret_cast<const bf16x8*>(&h1_s[rs][l15][32 + quad * 8]);
            floatx4 z[4];
            #pragma unroll
            for (int g = 0; g < 4; ++g)
                #pragma unroll
                for (int r = 0; r < 4; ++r)
                    z[g][r] = x_s[quad * 4 + r][t] * wxc[g] + bcs[g];
            #pragma unroll
            for (int g = 0; g < 4; ++g) z[g] = MFMA(A1a, Wf[0][g], z[g]);
            #pragma unroll
            for (int g = 0; g < 4; ++g) z[g] = MFMA(A1b, Wf[1][g], z[g]);
            #pragma unroll
            for (int r = 0; r < 4; ++r) {
                float hv = lstm_gate(z[0][r], z[1][r], z[2][r], z[3][r], cst[r]);
                h1_s[ws][quad * 4 + r][hcol] = f2bf(hv);
            }
            __threadfence_block();
            if (lane == 0) vp1[ct] = t + 1;
        }
    } else {
        // ================= layer-2 waves (consumer) =================
        bf16x8 Wf[4][4];                 // Wih2 (0..1) + Whh2 (2..3)
        float bcs[4];
        #pragma unroll
        for (int g = 0; g < 4; ++g) {
            const float sc = (g == 2) ? (-2.0f * LOG2E) : (-LOG2E);
            const int col = g * 64 + hcol;
            bcs[g] = (bih2[col] + bhh2[col]) * sc;
            #pragma unroll
            for (int kt = 0; kt < 2; ++kt) {
                const int koff = kt * 32 + quad * 8;
                union { short s[8]; bf16x8 v; } u0, u1;
                #pragma unroll
                for (int j = 0; j < 8; ++j) {
                    u0.s[j] = f2bf(Wih2[col * HID + koff + j] * sc);
                    u1.s[j] = f2bf(Whh2[col * HID + koff + j] * sc);
                }
                Wf[kt][g] = u0.v;
                Wf[2 + kt][g] = u1.v;
            }
        }
        float cst[4] = {0, 0, 0, 0};
        int m1 = 0, m2 = 0;
        for (int t = 0; t < SEQ; ++t) {
            const int rs = (t - 1) & 3;    // h1[t-1] ring slot
            // wait: h1[t-1] ready; peers' h2[t-2] ready (parity safety too)
            if (m1 < t || m2 < t) {
                do {
                    m1 = min4v(vp1);
                    m2 = min4v(vp2);
                } while (m1 < t || m2 < t);
            }
            asm volatile("" ::: "memory");
            const bf16x8 A1a = *reinterpret_cast<const bf16x8*>(&h1_s[rs][l15][quad * 8]);
            const bf16x8 A1b = *reinterpret_cast<const bf16x8*>(&h1_s[rs][l15][32 + quad * 8]);
            const bf16x8 A2a = *reinterpret_cast<const bf16x8*>(&h2_s[t & 1][l15][quad * 8]);
            const bf16x8 A2b = *reinterpret_cast<const bf16x8*>(&h2_s[t & 1][l15][32 + quad * 8]);
            floatx4 z[4];
            #pragma unroll
            for (int g = 0; g < 4; ++g)
                z[g] = floatx4{bcs[g], bcs[g], bcs[g], bcs[g]};
            #pragma unroll
            for (int g = 0; g < 4; ++g) z[g] = MFMA(A1a, Wf[0][g], z[g]);   // Wih2 @ h1[t-1]
            #pragma unroll
            for (int g = 0; g < 4; ++g) z[g] = MFMA(A1b, Wf[1][g], z[g]);
            #pragma unroll
            for (int g = 0; g < 4; ++g) z[g] = MFMA(A2a, Wf[2][g], z[g]);   // Whh2 @ h2[t-2]
            #pragma unroll
            for (int g = 0; g < 4; ++g) z[g] = MFMA(A2b, Wf[3][g], z[g]);
            const float m2f = (t == 0) ? 0.0f : 1.0f;  // discard bogus step at t=0
            #pragma unroll
            for (int r = 0; r < 4; ++r) {
                float cc = cst[r];
                float hv = lstm_gate(z[0][r], z[1][r], z[2][r], z[3][r], cc) * m2f;
                cst[r] = cc * m2f;
                h2_s[(t + 1) & 1][quad * 4 + r][hcol] = f2bf(hv);   // h2[t-1]
            }
            __threadfence_block();
            if (lane == 0) vp2[ct] = t + 1;
        }
        // ---- drain: virtual t=512 computes h2[511] -> x_s (as [16][64] f32) ----
        {
            int m1 = 0, m2 = 0;
            do {
                m1 = min4v(vp1);
                m2 = min4v(vp2);
            } while (m1 < SEQ || m2 < SEQ);
            asm volatile("" ::: "memory");
            const bf16x8 A1a = *reinterpret_cast<const bf16x8*>(&h1_s[(SEQ - 1) & 3][l15][quad * 8]);       // h1[511]
            const bf16x8 A1b = *reinterpret_cast<const bf16x8*>(&h1_s[(SEQ - 1) & 3][l15][32 + quad * 8]);
            const bf16x8 A2a = *reinterpret_cast<const bf16x8*>(&h2_s[SEQ & 1][l15][quad * 8]);             // h2[510]
            const bf16x8 A2b = *reinterpret_cast<const bf16x8*>(&h2_s[SEQ & 1][l15][32 + quad * 8]);
            floatx4 z[4];
            #pragma unroll
            for (int g = 0; g < 4; ++g) {
                z[g] = floatx4{bcs[g], bcs[g], bcs[g], bcs[g]};
                z[g] = MFMA(A1a, Wf[0][g], z[g]);
                z[g] = MFMA(A1b, Wf[1][g], z[g]);
                z[g] = MFMA(A2a, Wf[2][g], z[g]);
                z[g] = MFMA(A2b, Wf[3][g], z[g]);
            }
            float* h2f = &x_s[0][0];       // L1 waves are done with x_s (prog1>=512)
            #pragma unroll
            for (int r = 0; r < 4; ++r) {
                float cc = cst[r];
                h2f[(quad * 4 + r) * HID + hcol] = lstm_gate(z[0][r], z[1][r], z[2][r], z[3][r], cc);
            }
        }
    }
    __syncthreads();

    // ---- epilogue: relu(h2 @ Wd1^T + bd1) @ Wd2^T + bd2 ----
    const float* h2f = &x_s[0][0];
    for (int idx = tid; idx < 16 * 32; idx += 512) {
        const int b = idx >> 5, o = idx & 31;
        float acc = bd1[o];
        #pragma unroll 8
        for (int k = 0; k < HID; ++k) acc += h2f[b * HID + k] * Wd1[o * HID + k];
        y1_s[b][o] = fmaxf(acc, 0.0f);
    }
    __syncthreads();
    for (int idx = tid; idx < 16 * 24; idx += 512) {
        const int b = idx / 24, o = idx - b * 24;
        float acc = bd2[o];
        #pragma unroll 8
        for (int k = 0; k < 32; ++k) acc += y1_s[b][k] * Wd2[o * 32 + k];
        out[(size_t)(b0 + b) * 24 + o] = acc;
    }
}

extern "C" void kernel_launch(void* const* d_in, const int* in_sizes, int n_in,
                              void* d_out, int out_size, void* d_ws, size_t ws_size,
                              hipStream_t stream) {
    const float* x    = (const float*)d_in[0];
    const float* Wih1 = (const float*)d_in[1];
    const float* Whh1 = (const float*)d_in[2];
    const float* bih1 = (const float*)d_in[3];
    const float* bhh1 = (const float*)d_in[4];
    const float* Wih2 = (const float*)d_in[5];
    const float* Whh2 = (const float*)d_in[6];
    const float* bih2 = (const float*)d_in[7];
    const float* bhh2 = (const float*)d_in[8];
    const float* Wd1  = (const float*)d_in[9];
    const float* bd1  = (const float*)d_in[10];
    const float* Wd2  = (const float*)d_in[11];
    const float* bd2  = (const float*)d_in[12];
    float* out = (float*)d_out;

    lstm_fused<<<256, 512, 0, stream>>>(x, Wih1, Whh1, bih1, bhh1,
                                        Wih2, Whh2, bih2, bhh2,
                                        Wd1, bd1, Wd2, bd2, out);
}

// Round 9
// 483.242 us; speedup vs baseline: 1.2206x; 1.2206x over previous
//
#include <hip/hip_runtime.h>

// Fused 2-layer LSTM (B=4096, S=512, H=64) + dense(64->32 relu)->dense(32->24).
// R12: R9/R10 structure (512 thr, 8 waves = (layer, col-tile), 8 rows/WG
// row-packed, grid=512 = 2 WGs/CU, 1 barrier/step) with L2's Wih2 B-frags
// moved from registers to a shared, pre-scaled, XOR-swizzled LDS copy.
// WHY (occupancy ledger, R3-R11): waves/CU halves at TOTAL regs (VGPR+AGPR)
// {64,128,256} (m69). R3/R10 at arch-76 still ran 1 WG/CU (occ 23%) because
// the compiler AGPR-izes Wf + accumulators: L2 total ~140 > 128. R9's 64-VGPR
// clamp accidentally capped total at 128 -> 16 waves/CU (occ 38%) -> best
// multi-WG time (471us) DESPITE 5-reg spill. So: design both branches to
// total <=128 with no spill. Dropping Wih2 (32 regs) from L2 gives L2 ~105,
// L1 ~75. Cost: +8 ds_read_b128/step on L2 waves (~96cy issue) -- cheap vs
// the second WG's uncorrelated-barrier overlap (one WG computes while the
// other drains; single-WG scheduling variants R4-R8,R11 all failed).
// Wih2 LDS layout: raw row-major [256 rows][64 cols] bf16 pre-scaled by the
// gate constant, 16B chunks XOR-swizzled byte^=((row&7)<<4) so the 128B row
// stride doesn't 16-way bank-conflict on frag reads (G4/T2).
// Row packing: batch row b (0..7) -> MFMA A-row (b>>1)*4+(b&1); C-layout puts
// each lane's 2 valid rows in z[g][0..1] - no shuffle, half gate work/wave.
// Recurrence: parity double-buffered h1/h2, layer-2 delayed 1 step
// (z2[t-1] = b2 + Wih2@h1[t-1] + Whh2@h2[t-2]).
// Gate math: 5 exp + 2 rcp per element (i/f/g denominators merged).
// LDS 59.5KB: >163840/3 so 2 WGs/CU is the hard cap; grid=512 = exactly 2/CU.

typedef __attribute__((ext_vector_type(8))) short bf16x8;
typedef __attribute__((ext_vector_type(4))) float floatx4;

#define SEQ 512
#define HID 64
#define LOG2E 1.4426950408889634f

__device__ inline floatx4 MFMA(bf16x8 a, bf16x8 b, floatx4 c) {
    return __builtin_amdgcn_mfma_f32_16x16x32_bf16(a, b, c, 0, 0, 0);
}
__device__ inline short f2bf(float f) {
    __bf16 b = (__bf16)f;
    return __builtin_bit_cast(short, b);
}
__device__ inline float exp2_fast(float x) {
#if __has_builtin(__builtin_amdgcn_exp2f)
    return __builtin_amdgcn_exp2f(x);
#else
    return __expf(x * 0.6931471805599453f);
#endif
}
__device__ inline float rcp_fast(float x) { return __builtin_amdgcn_rcpf(x); }

// z* pre-scaled: zi=-i*log2e, zf=-f*log2e, zg=-2g*log2e, zo=-o*log2e.
// c' = [c*(1+ei)(1+eg) + (1-eg)(1+ef)] / [(1+ef)(1+ei)(1+eg)]  (merged rcp)
// h  = sigm(o)*tanh(c') = (1-ec)/((1+eo)(1+ec)),  ec = e^{-2c'} (clamped)
__device__ inline float lstm_gate(float zi, float zf, float zg, float zo, float& c) {
    float ei = exp2_fast(zi);
    float ef = exp2_fast(zf);
    float eg = exp2_fast(zg);
    float eo = exp2_fast(zo);
    float P  = (1.0f + ei) * (1.0f + eg);
    float F  = 1.0f + ef;
    float num = c * P + (1.0f - eg) * F;
    c = num * rcp_fast(P * F);
    float ec = exp2_fast(fminf(c * (-2.0f * LOG2E), 40.0f));
    return (1.0f - ec) * rcp_fast((1.0f + eo) * (1.0f + ec));
}

__global__ __launch_bounds__(512, 2)
void lstm_fused(
    const float* __restrict__ x,
    const float* __restrict__ Wih1, const float* __restrict__ Whh1,
    const float* __restrict__ bih1, const float* __restrict__ bhh1,
    const float* __restrict__ Wih2, const float* __restrict__ Whh2,
    const float* __restrict__ bih2, const float* __restrict__ bhh2,
    const float* __restrict__ Wd1,  const float* __restrict__ bd1,
    const float* __restrict__ Wd2,  const float* __restrict__ bd2,
    float* __restrict__ out)
{
    const int tid  = threadIdx.x;
    const int wid  = tid >> 6;        // 0..7
    const int ct   = wid & 3;         // column-tile (h-cols [16ct,16ct+16))
    const int is2  = wid >> 2;        // waves 0-3: layer-1, 4-7: layer-2
    const int lane = tid & 63;
    const int l15  = lane & 15;
    const int quad = lane >> 4;
    const int b0   = blockIdx.x * 8;

    // Per-lane rows: batch rows {2q, 2q+1} stored at A-rows {4q, 4q+1}.
    __shared__ __align__(16) float x_s[8][516];
    __shared__ __align__(16) short h1_s[2][16][72];
    __shared__ __align__(16) short h2_s[2][16][72];
    __shared__ float y1_s[8][32];
    __shared__ __align__(16) char wih2_lds[256 * 64 * 2];   // bf16, pre-scaled, swizzled

    // ---- stage x tile (8 rows x 512 f32): one wave per row ----
    {
        const int row = wid;
        const int c0  = lane * 8;
        const float4* src = reinterpret_cast<const float4*>(x + (size_t)(b0 + row) * SEQ + c0);
        float4* dst = reinterpret_cast<float4*>(&x_s[row][c0]);
        dst[0] = src[0];
        dst[1] = src[1];
    }
    // ---- stage Wih2 -> LDS: row r holds Wih2[r][0..63]*sc(g), swizzled ----
    {
        const int r  = tid >> 1;            // 0..255 (= gate-col index)
        const int hh = tid & 1;             // K-half
        const int g  = r >> 6;
        const float sc = (g == 2) ? (-2.0f * LOG2E) : (-LOG2E);
        const float* src = Wih2 + r * HID + hh * 32;
        #pragma unroll
        for (int cch = 0; cch < 4; ++cch) {
            union { short s[8]; bf16x8 v; } u;
            #pragma unroll
            for (int j = 0; j < 8; ++j) u.s[j] = f2bf(src[cch * 8 + j] * sc);
            const int dst = (r * 128 + hh * 64 + cch * 16) ^ ((r & 7) << 4);
            *reinterpret_cast<bf16x8*>(wih2_lds + dst) = u.v;
        }
    }
    // Zero h buffers: also keeps A-rows {2,3,6,7,10,11,14,15} zero forever.
    for (int i = tid; i < 2 * 16 * 72; i += 512) {
        (&h1_s[0][0][0])[i] = 0;
        (&h2_s[0][0][0])[i] = 0;
    }

    const int hcol = ct * 16 + l15;
    const int ar0  = quad * 4;        // A-row of this lane's first batch row (2q)
    const int xr0  = 2 * quad;        // batch row of z[g][0]

    if (!is2) {
        // ================= layer-1 waves =================
        bf16x8 Wf[2][4];                 // Whh1 K-halves: 32 regs
        float wxc[4], bcs[4];
        #pragma unroll
        for (int g = 0; g < 4; ++g) {
            const float sc = (g == 2) ? (-2.0f * LOG2E) : (-LOG2E);
            const int col = g * 64 + hcol;
            wxc[g] = Wih1[col] * sc;
            bcs[g] = (bih1[col] + bhh1[col]) * sc;
            #pragma unroll
            for (int kt = 0; kt < 2; ++kt) {
                const int koff = kt * 32 + quad * 8;
                union { short s[8]; bf16x8 v; } u;
                #pragma unroll
                for (int j = 0; j < 8; ++j)
                    u.s[j] = f2bf(Whh1[col * HID + koff + j] * sc);
                Wf[kt][g] = u.v;
            }
        }
        float cst[2] = {0, 0};
        __syncthreads();                   // covers x, Wih2, h-zero staging
        #pragma unroll 2
        for (int t = 0; t < SEQ; ++t) {
            const int pr1 = (t + 1) & 1;   // holds h1[t-1]
            const int pr2 = t & 1;         // receives h1[t]
            const bf16x8 A1a = *reinterpret_cast<const bf16x8*>(&h1_s[pr1][l15][quad * 8]);
            const bf16x8 A1b = *reinterpret_cast<const bf16x8*>(&h1_s[pr1][l15][32 + quad * 8]);
            const float xa = x_s[xr0][t];
            const float xb = x_s[xr0 + 1][t];
            floatx4 z[4];
            #pragma unroll
            for (int g = 0; g < 4; ++g) {
                z[g] = floatx4{bcs[g], bcs[g], bcs[g], bcs[g]};
                z[g][0] += xa * wxc[g];
                z[g][1] += xb * wxc[g];
            }
            #pragma unroll
            for (int g = 0; g < 4; ++g) z[g] = MFMA(A1a, Wf[0][g], z[g]);
            #pragma unroll
            for (int g = 0; g < 4; ++g) z[g] = MFMA(A1b, Wf[1][g], z[g]);
            // rows 2q, 2q+1 live in z[g][0], z[g][1] (A-row packing)
            float hv = lstm_gate(z[0][0], z[1][0], z[2][0], z[3][0], cst[0]);
            h1_s[pr2][ar0][hcol] = f2bf(hv);
            hv = lstm_gate(z[0][1], z[1][1], z[2][1], z[3][1], cst[1]);
            h1_s[pr2][ar0 + 1][hcol] = f2bf(hv);
            __syncthreads();
        }
        __syncthreads();                  // matches L2 drain barrier
    } else {
        // ================= layer-2 waves =================
        bf16x8 Wf[2][4];                 // Whh2 K-halves only: 32 regs (Wih2 in LDS)
        float bcs[4];
        #pragma unroll
        for (int g = 0; g < 4; ++g) {
            const float sc = (g == 2) ? (-2.0f * LOG2E) : (-LOG2E);
            const int col = g * 64 + hcol;
            bcs[g] = (bih2[col] + bhh2[col]) * sc;
            #pragma unroll
            for (int kt = 0; kt < 2; ++kt) {
                const int koff = kt * 32 + quad * 8;
                union { short s[8]; bf16x8 v; } u;
                #pragma unroll
                for (int j = 0; j < 8; ++j)
                    u.s[j] = f2bf(Whh2[col * HID + koff + j] * sc);
                Wf[kt][g] = u.v;
            }
        }
        // Per-lane swizzled Wih2 frag addresses (row = g*64+hcol, K-chunk = kt).
        int wadr[2][4];
        #pragma unroll
        for (int g = 0; g < 4; ++g) {
            const int wrow = g * 64 + hcol;
            #pragma unroll
            for (int kt = 0; kt < 2; ++kt)
                wadr[kt][g] = (wrow * 128 + kt * 64 + quad * 16) ^ ((wrow & 7) << 4);
        }
        float cst[2] = {0, 0};
        __syncthreads();                   // covers x, Wih2, h-zero staging
        #pragma unroll 2
        for (int t = 0; t < SEQ; ++t) {
            const int pr1 = (t + 1) & 1;   // h1[t-1]; receives h2[t-1]
            const int pr2 = t & 1;         // holds h2[t-2]
            const bf16x8 A1a = *reinterpret_cast<const bf16x8*>(&h1_s[pr1][l15][quad * 8]);
            const bf16x8 A1b = *reinterpret_cast<const bf16x8*>(&h1_s[pr1][l15][32 + quad * 8]);
            const bf16x8 A2a = *reinterpret_cast<const bf16x8*>(&h2_s[pr2][l15][quad * 8]);
            const bf16x8 A2b = *reinterpret_cast<const bf16x8*>(&h2_s[pr2][l15][32 + quad * 8]);
            floatx4 z[4];
            #pragma unroll
            for (int g = 0; g < 4; ++g)
                z[g] = floatx4{bcs[g], bcs[g], bcs[g], bcs[g]};
            #pragma unroll
            for (int g = 0; g < 4; ++g) {   // Wih2 @ h1[t-1], B-frags from LDS
                const bf16x8 B0 = *reinterpret_cast<const bf16x8*>(wih2_lds + wadr[0][g]);
                z[g] = MFMA(A1a, B0, z[g]);
            }
            #pragma unroll
            for (int g = 0; g < 4; ++g) {
                const bf16x8 B1 = *reinterpret_cast<const bf16x8*>(wih2_lds + wadr[1][g]);
                z[g] = MFMA(A1b, B1, z[g]);
            }
            #pragma unroll
            for (int g = 0; g < 4; ++g) z[g] = MFMA(A2a, Wf[0][g], z[g]);   // Whh2 @ h2[t-2]
            #pragma unroll
            for (int g = 0; g < 4; ++g) z[g] = MFMA(A2b, Wf[1][g], z[g]);
            const float m2 = (t == 0) ? 0.0f : 1.0f;  // discard bogus step at t=0
            float cc = cst[0];
            float hv = lstm_gate(z[0][0], z[1][0], z[2][0], z[3][0], cc) * m2;
            cst[0] = cc * m2;
            h2_s[pr1][ar0][hcol] = f2bf(hv);
            cc = cst[1];
            hv = lstm_gate(z[0][1], z[1][1], z[2][1], z[3][1], cc) * m2;
            cst[1] = cc * m2;
            h2_s[pr1][ar0 + 1][hcol] = f2bf(hv);
            __syncthreads();
        }
        // ---- drain: layer 2 for t = SEQ-1 (h1[511] visible after last loop barrier) ----
        {
            const bf16x8 A1a = *reinterpret_cast<const bf16x8*>(&h1_s[1][l15][quad * 8]);       // h1[511]
            const bf16x8 A1b = *reinterpret_cast<const bf16x8*>(&h1_s[1][l15][32 + quad * 8]);
            const bf16x8 A2a = *reinterpret_cast<const bf16x8*>(&h2_s[0][l15][quad * 8]);       // h2[510]
            const bf16x8 A2b = *reinterpret_cast<const bf16x8*>(&h2_s[0][l15][32 + quad * 8]);
            floatx4 z[4];
            #pragma unroll
            for (int g = 0; g < 4; ++g) {
                z[g] = floatx4{bcs[g], bcs[g], bcs[g], bcs[g]};
                const bf16x8 B0 = *reinterpret_cast<const bf16x8*>(wih2_lds + wadr[0][g]);
                const bf16x8 B1 = *reinterpret_cast<const bf16x8*>(wih2_lds + wadr[1][g]);
                z[g] = MFMA(A1a, B0, z[g]);
                z[g] = MFMA(A1b, B1, z[g]);
                z[g] = MFMA(A2a, Wf[0][g], z[g]);
                z[g] = MFMA(A2b, Wf[1][g], z[g]);
            }
            float* h2f = &x_s[0][0];       // repurpose x stage as [8][64] f32
            float cc = cst[0];
            h2f[(size_t)xr0 * HID + hcol] = lstm_gate(z[0][0], z[1][0], z[2][0], z[3][0], cc);
            cc = cst[1];
            h2f[(size_t)(xr0 + 1) * HID + hcol] = lstm_gate(z[0][1], z[1][1], z[2][1], z[3][1], cc);
        }
        __syncthreads();
    }

    // ---- epilogue: relu(h2 @ Wd1^T + bd1) @ Wd2^T + bd2 ----
    const float* h2f = &x_s[0][0];
    for (int idx = tid; idx < 8 * 32; idx += 512) {
        const int b = idx >> 5, o = idx & 31;
        float acc = bd1[o];
        #pragma unroll 8
        for (int k = 0; k < HID; ++k) acc += h2f[b * HID + k] * Wd1[o * HID + k];
        y1_s[b][o] = fmaxf(acc, 0.0f);
    }
    __syncthreads();
    for (int idx = tid; idx < 8 * 24; idx += 512) {
        const int b = idx / 24, o = idx - b * 24;
        float acc = bd2[o];
        #pragma unroll 8
        for (int k = 0; k < 32; ++k) acc += y1_s[b][k] * Wd2[o * 32 + k];
        out[(size_t)(b0 + b) * 24 + o] = acc;
    }
}

extern "C" void kernel_launch(void* const* d_in, const int* in_sizes, int n_in,
                              void* d_out, int out_size, void* d_ws, size_t ws_size,
                              hipStream_t stream) {
    const float* x    = (const float*)d_in[0];
    const float* Wih1 = (const float*)d_in[1];
    const float* Whh1 = (const float*)d_in[2];
    const float* bih1 = (const float*)d_in[3];
    const float* bhh1 = (const float*)d_in[4];
    const float* Wih2 = (const float*)d_in[5];
    const float* Whh2 = (const float*)d_in[6];
    const float* bih2 = (const float*)d_in[7];
    const float* bhh2 = (const float*)d_in[8];
    const float* Wd1  = (const float*)d_in[9];
    const float* bd1  = (const float*)d_in[10];
    const float* Wd2  = (const float*)d_in[11];
    const float* bd2  = (const float*)d_in[12];
    float* out = (float*)d_out;

    lstm_fused<<<512, 512, 0, stream>>>(x, Wih1, Whh1, bih1, bhh1,
                                        Wih2, Whh2, bih2, bhh2,
                                        Wd1, bd1, Wd2, bd2, out);
}